// Round 1
// baseline (12.492 us; speedup 1.0000x reference)
//
#include <hip/hip_runtime.h>

#define BATCH 4096
#define NUM_CLASSES 10000
#define FEAT_DIM 512

// Kernel 1: one 64-lane wave per sample. Each lane handles 8 contiguous floats
// (2 x float4) of the 512-float row. Per-block (4 samples) partial -> ws.
__global__ __launch_bounds__(256) void center_loss_partial(
    const float* __restrict__ x,
    const int* __restrict__ labels,
    const float* __restrict__ centers,
    float* __restrict__ partial)
{
    const int wave = threadIdx.x >> 6;   // 0..3
    const int lane = threadIdx.x & 63;   // 0..63
    const int sample = blockIdx.x * 4 + wave;   // grid = 1024 -> sample < 4096 always

    const int label = labels[sample];    // wave-uniform broadcast load

    const float4* __restrict__ xr = (const float4*)(x + (size_t)sample * FEAT_DIM);
    const float4* __restrict__ cr = (const float4*)(centers + (size_t)label * FEAT_DIM);

    // 512 floats = 128 float4s; 64 lanes x 2 float4 each, coalesced.
    float4 a0 = xr[lane * 2 + 0];
    float4 a1 = xr[lane * 2 + 1];
    float4 b0 = cr[lane * 2 + 0];
    float4 b1 = cr[lane * 2 + 1];

    float acc = 0.0f;
    float d;
    d = a0.x - b0.x; acc += d * d;
    d = a0.y - b0.y; acc += d * d;
    d = a0.z - b0.z; acc += d * d;
    d = a0.w - b0.w; acc += d * d;
    d = a1.x - b1.x; acc += d * d;
    d = a1.y - b1.y; acc += d * d;
    d = a1.z - b1.z; acc += d * d;
    d = a1.w - b1.w; acc += d * d;

    // wave64 butterfly reduce
    #pragma unroll
    for (int off = 32; off > 0; off >>= 1)
        acc += __shfl_down(acc, off, 64);

    __shared__ float s[4];
    if (lane == 0) s[wave] = acc;
    __syncthreads();
    if (threadIdx.x == 0)
        partial[blockIdx.x] = s[0] + s[1] + s[2] + s[3];
}

// Kernel 2: single 1024-thread block reduces 1024 partials, writes loss.
__global__ __launch_bounds__(1024) void center_loss_reduce(
    const float* __restrict__ partial,
    float* __restrict__ out)
{
    const int tid = threadIdx.x;
    float v = partial[tid];

    #pragma unroll
    for (int off = 32; off > 0; off >>= 1)
        v += __shfl_down(v, off, 64);

    __shared__ float s[16];
    if ((tid & 63) == 0) s[tid >> 6] = v;
    __syncthreads();

    if (tid < 64) {
        float t = (tid < 16) ? s[tid] : 0.0f;
        #pragma unroll
        for (int off = 32; off > 0; off >>= 1)
            t += __shfl_down(t, off, 64);
        if (tid == 0)
            out[0] = t / (float)BATCH;
    }
}

extern "C" void kernel_launch(void* const* d_in, const int* in_sizes, int n_in,
                              void* d_out, int out_size, void* d_ws, size_t ws_size,
                              hipStream_t stream) {
    const float* x       = (const float*)d_in[0];
    const int*   labels  = (const int*)d_in[1];
    const float* centers = (const float*)d_in[2];
    float* out = (float*)d_out;
    float* partial = (float*)d_ws;   // 1024 floats = 4 KB of scratch

    center_loss_partial<<<BATCH / 4, 256, 0, stream>>>(x, labels, centers, partial);
    center_loss_reduce<<<1, 1024, 0, stream>>>(partial, out);
}